// Round 4
// baseline (278.943 us; speedup 1.0000x reference)
//
#include <hip/hip_runtime.h>
#include <stdint.h>

// Problem constants
#define M_DIM 32768
#define N_DIM 1024
#define K_DIM 1024

using int32x4 = __attribute__((ext_vector_type(4))) int;
using int32x16 = __attribute__((ext_vector_type(16))) int;

__device__ __forceinline__ void gload_lds16(const void* g, void* l) {
  __builtin_amdgcn_global_load_lds(
      (const __attribute__((address_space(1))) void*)g,
      (__attribute__((address_space(3))) void*)l,
      16 /*bytes*/, 0 /*offset*/, 0 /*aux*/);
}

// ---------------- Kernel 1: fused weight-unpack + activation-quantize ----------------
// Blocks [0,512): unpack int4 weights -> int8 [N, K].
//   HARNESS NOTE: integer inputs arrive as int32 — weight_packed is 524288 int32
//   elements, ONE packed byte (0..255) per int32. Byte j of row r: low nibble ->
//   w[r][2j], high nibble -> w[r][2j+1]. sext4(v) = ((v&0xF)^8)-8.
// Blocks [512, 33280): quantize fp32 x -> int8: clip(rint(x*20), -127, 127).
__global__ __launch_bounds__(256) void prep_kernel(const float* __restrict__ x,
                                                   const int4* __restrict__ wp,
                                                   uint32_t* __restrict__ q,
                                                   uint2* __restrict__ w8) {
  const int bx = blockIdx.x;
  const int tid = threadIdx.x;
  if (bx < 512) {
    const int g = bx * 256 + tid;  // 4 packed bytes -> 8 int8
    const int4 p = wp[g];
    int w0 = ((p.x & 0xF) ^ 8) - 8;
    int w1 = (((p.x >> 4) & 0xF) ^ 8) - 8;
    int w2 = ((p.y & 0xF) ^ 8) - 8;
    int w3 = (((p.y >> 4) & 0xF) ^ 8) - 8;
    int w4 = ((p.z & 0xF) ^ 8) - 8;
    int w5 = (((p.z >> 4) & 0xF) ^ 8) - 8;
    int w6 = ((p.w & 0xF) ^ 8) - 8;
    int w7 = (((p.w >> 4) & 0xF) ^ 8) - 8;
    uint2 st;
    st.x = (uint32_t)(w0 & 0xFF) | ((uint32_t)(w1 & 0xFF) << 8) |
           ((uint32_t)(w2 & 0xFF) << 16) | ((uint32_t)(w3 & 0xFF) << 24);
    st.y = (uint32_t)(w4 & 0xFF) | ((uint32_t)(w5 & 0xFF) << 8) |
           ((uint32_t)(w6 & 0xFF) << 16) | ((uint32_t)(w7 & 0xFF) << 24);
    w8[g] = st;
  } else {
    const int g = (bx - 512) * 256 + tid;  // one float4 per thread
    const float4 v = ((const float4*)x)[g];
    int a0 = (int)rintf(fminf(fmaxf(v.x * 20.0f, -127.0f), 127.0f));
    int a1 = (int)rintf(fminf(fmaxf(v.y * 20.0f, -127.0f), 127.0f));
    int a2 = (int)rintf(fminf(fmaxf(v.z * 20.0f, -127.0f), 127.0f));
    int a3 = (int)rintf(fminf(fmaxf(v.w * 20.0f, -127.0f), 127.0f));
    q[g] = (uint32_t)(a0 & 0xFF) | ((uint32_t)(a1 & 0xFF) << 8) |
           ((uint32_t)(a2 & 0xFF) << 16) | ((uint32_t)(a3 & 0xFF) << 24);
  }
}

// ---------------- Kernel 2: int8 GEMM, producer/consumer, BK=128 ----------------
// C[m][n] = (sum_k A[m][k]*W[n][k]) * 5e-4 + bias[n], f32 out.
// Block = 320 threads: waves 0..3 = consumers (2x2 grid of 64x64 sub-tiles,
// mfma_i32_32x32x32_i8, 16 MFMA/wave/window), wave 4 = producer (global_load_lds
// staging only; consumers issue NO vm ops -> no defeating vmcnt(0) on them).
// BK=128: 8 windows of K instead of 16 — halves the per-window wall count
// (barrier skew + producer drain), doubling MFMA content per window. LDS =
// 2 buffers x (16KB A + 16KB B) = 64 KB -> 2 blocks/CU so the other block's
// waves cover each block's barrier wall.
// Schedule (8 barriers both paths): producer stages t0->b0, vmcnt(0), B0;
// then for kk=0..6: issue t(kk+1)->buf (kk+1)&1 (32 loads) at window start,
// vmcnt(0) + barrier at window end — a full window (~1.5k cyc) covers L3
// latency (A8/W8 are L3-resident from prep). Consumers: barrier, 16x
// ds_read_b128, 16x MFMA per window.
// LDS chunk swizzle (8 chunks/row): LDS[r][c] = G[r][c ^ (r&7)]; consumer reads
// chunk (ks*2+hl) ^ (rA&7) — spreads a b128 column read across all 32 banks per
// 8-row stripe. Staging stays lane-contiguous (gload_lds requirement).
// Grid swizzle: bx&7 = XCD (round-robin dispatch) owns m-tiles [32x,32x+32) so
// each A line is L2-filled on exactly one XCD; the 8 n-blocks sharing an m-tile
// are co-resident there -> ~1x A fabric traffic.
__global__ __launch_bounds__(320, 2) void gemm_kernel(const uint8_t* __restrict__ A,
                                                      const uint8_t* __restrict__ W,
                                                      const float* __restrict__ bias,
                                                      float* __restrict__ out) {
  __shared__ uint8_t sA[2][128 * 128];
  __shared__ uint8_t sB[2][128 * 128];

  const int tid = threadIdx.x;
  const int bx = blockIdx.x;
  const int xcd = bx & 7;
  const int tt = bx >> 3;
  const int m0 = (xcd * 32 + (tt >> 3)) * 128;
  const int n0 = (tt & 7) * 128;

  if (tid >= 256) {
    // ================= producer wave =================
    const int lane = tid - 256;
    const uint8_t* gA[16];
    const uint8_t* gB[16];
    uint32_t lofs[16];
#pragma unroll
    for (int j = 0; j < 16; j++) {
      const int li = j * 64 + lane;      // 16B-chunk id within 1024-chunk tile
      const int r = li >> 3, c = li & 7; // row, LDS chunk slot
      const int cg = c ^ (r & 7);        // swizzled global chunk
      gA[j] = A + (size_t)(m0 + r) * K_DIM + cg * 16;
      gB[j] = W + (size_t)(n0 + r) * K_DIM + cg * 16;
      lofs[j] = (uint32_t)li * 16;
    }
    // Prologue: tile 0 -> buf0 (32 loads), drain, barrier B0.
#pragma unroll
    for (int j = 0; j < 16; j++) gload_lds16(gA[j], &sA[0][0] + lofs[j]);
#pragma unroll
    for (int j = 0; j < 16; j++) gload_lds16(gB[j], &sB[0][0] + lofs[j]);
    asm volatile("s_waitcnt vmcnt(0)\n\ts_barrier" ::: "memory");
#pragma unroll 1
    for (int kk = 0; kk < 7; kk++) {
      // Issue tile kk+1 at window-kk start (buf (kk+1)&1 was released at B(kk)),
      // then drain + barrier at window end: full window covers load latency.
      const int off = (kk + 1) * 128;
      const uint32_t bo = (uint32_t)((kk + 1) & 1) * 16384;
#pragma unroll
      for (int j = 0; j < 16; j++) gload_lds16(gA[j] + off, &sA[0][0] + bo + lofs[j]);
#pragma unroll
      for (int j = 0; j < 16; j++) gload_lds16(gB[j] + off, &sB[0][0] + bo + lofs[j]);
      asm volatile("s_waitcnt vmcnt(0)\n\ts_barrier" ::: "memory");
    }
    // producer done (8 barriers total, matching consumers)
  } else {
    // ================= consumer waves =================
    const int lane = tid & 63;
    const int wid = tid >> 6;   // 0..3
    const int wm = wid >> 1;    // m-half of 128-tile
    const int wn = wid & 1;     // n-half
    const int rl = lane & 31;   // row/col within 32-tile
    const int hl = lane >> 5;   // k-half selector

    // Fragment LDS byte offsets (A: rows m, B: rows n), swizzle-corrected.
    uint32_t offA[2][4], offB[2][4];
#pragma unroll
    for (int mt = 0; mt < 2; mt++)
#pragma unroll
      for (int ks = 0; ks < 4; ks++) {
        const int rA = wm * 64 + mt * 32 + rl;
        const int cA = (ks * 2 + hl) ^ (rA & 7);
        offA[mt][ks] = (uint32_t)(rA * 128 + cA * 16);
        const int rB = wn * 64 + mt * 32 + rl;
        const int cB = (ks * 2 + hl) ^ (rB & 7);
        offB[mt][ks] = (uint32_t)(rB * 128 + cB * 16);
      }

    int32x16 acc[2][2] = {};
#pragma unroll 1
    for (int kk = 0; kk < 8; kk++) {
      asm volatile("s_barrier" ::: "memory");  // B(kk): tile kk resident in buf kk&1
      const uint8_t* pA = &sA[0][0] + (uint32_t)(kk & 1) * 16384;
      const uint8_t* pB = &sB[0][0] + (uint32_t)(kk & 1) * 16384;
#pragma unroll
      for (int ks = 0; ks < 4; ks++) {
        int32x4 a0 = *(const int32x4*)(pA + offA[0][ks]);
        int32x4 a1 = *(const int32x4*)(pA + offA[1][ks]);
        int32x4 b0 = *(const int32x4*)(pB + offB[0][ks]);
        int32x4 b1 = *(const int32x4*)(pB + offB[1][ks]);
        acc[0][0] = __builtin_amdgcn_mfma_i32_32x32x32_i8(a0, b0, acc[0][0], 0, 0, 0);
        acc[0][1] = __builtin_amdgcn_mfma_i32_32x32x32_i8(a0, b1, acc[0][1], 0, 0, 0);
        acc[1][0] = __builtin_amdgcn_mfma_i32_32x32x32_i8(a1, b0, acc[1][0], 0, 0, 0);
        acc[1][1] = __builtin_amdgcn_mfma_i32_32x32x32_i8(a1, b1, acc[1][1], 0, 0, 0);
      }
    }

    // Epilogue. 32x32 C/D layout: col = lane&31, row = (reg&3) + 8*(reg>>2) + 4*(lane>>5).
    float bv[2];
#pragma unroll
    for (int nt = 0; nt < 2; nt++) bv[nt] = bias[n0 + wn * 64 + nt * 32 + rl];

#pragma unroll
    for (int mt = 0; mt < 2; mt++) {
#pragma unroll
      for (int nt = 0; nt < 2; nt++) {
        const int n_g = n0 + wn * 64 + nt * 32 + rl;
        const int mbase = m0 + wm * 64 + mt * 32 + 4 * hl;
#pragma unroll
        for (int reg = 0; reg < 16; reg++) {
          const int m_g = mbase + (reg & 3) + 8 * (reg >> 2);
          const float v = (float)acc[mt][nt][reg] * 0.0005f + bv[nt];
          // lanes 0..31 cover 32 consecutive n -> full 128B lines; write-once data.
          __builtin_nontemporal_store(v, &out[(size_t)m_g * N_DIM + n_g]);
        }
      }
    }
  }
}

extern "C" void kernel_launch(void* const* d_in, const int* in_sizes, int n_in,
                              void* d_out, int out_size, void* d_ws, size_t ws_size,
                              hipStream_t stream) {
  const float* x = (const float*)d_in[0];
  const int4* wp = (const int4*)d_in[1];   // int32 per packed byte (harness int rule)
  const float* bias = (const float*)d_in[2];
  float* out = (float*)d_out;

  uint8_t* A8 = (uint8_t*)d_ws;                       // 32768*1024 int8 = 32 MiB
  uint8_t* W8 = A8 + (size_t)M_DIM * K_DIM;           // 1024*1024 int8 = 1 MiB

  // K1: fused unpack (512 blocks) + quantize (32768 blocks)
  prep_kernel<<<512 + (M_DIM * K_DIM) / (4 * 256), 256, 0, stream>>>(
      x, wp, (uint32_t*)A8, (uint2*)W8);
  // K2: GEMM. grid = (M/128)*(N/128) = 2048, 320 threads (4 consumer + 1 producer waves)
  gemm_kernel<<<(M_DIM / 128) * (N_DIM / 128), 320, 0, stream>>>(A8, W8, bias, out);
}

// Round 7
// 274.069 us; speedup vs baseline: 1.0178x; 1.0178x over previous
//
#include <hip/hip_runtime.h>
#include <stdint.h>

// Problem constants
#define M_DIM 32768
#define N_DIM 1024
#define K_DIM 1024

using int32x4 = __attribute__((ext_vector_type(4))) int;
using int32x16 = __attribute__((ext_vector_type(16))) int;

__device__ __forceinline__ void gload_lds16(const void* g, void* l) {
  __builtin_amdgcn_global_load_lds(
      (const __attribute__((address_space(1))) void*)g,
      (__attribute__((address_space(3))) void*)l,
      16 /*bytes*/, 0 /*offset*/, 0 /*aux*/);
}

// ---------------- Kernel 1: fused weight-unpack + activation-quantize ----------------
// Blocks [0,512): unpack int4 weights -> int8 [N, K].
//   HARNESS NOTE: integer inputs arrive as int32 — weight_packed is 524288 int32
//   elements, ONE packed byte (0..255) per int32. Byte j of row r: low nibble ->
//   w[r][2j], high nibble -> w[r][2j+1]. sext4(v) = ((v&0xF)^8)-8.
// Blocks [512, 33280): quantize fp32 x -> int8: clip(rint(x*20), -127, 127).
__global__ __launch_bounds__(256) void prep_kernel(const float* __restrict__ x,
                                                   const int4* __restrict__ wp,
                                                   uint32_t* __restrict__ q,
                                                   uint2* __restrict__ w8) {
  const int bx = blockIdx.x;
  const int tid = threadIdx.x;
  if (bx < 512) {
    const int g = bx * 256 + tid;  // 4 packed bytes -> 8 int8
    const int4 p = wp[g];
    int w0 = ((p.x & 0xF) ^ 8) - 8;
    int w1 = (((p.x >> 4) & 0xF) ^ 8) - 8;
    int w2 = ((p.y & 0xF) ^ 8) - 8;
    int w3 = (((p.y >> 4) & 0xF) ^ 8) - 8;
    int w4 = ((p.z & 0xF) ^ 8) - 8;
    int w5 = (((p.z >> 4) & 0xF) ^ 8) - 8;
    int w6 = ((p.w & 0xF) ^ 8) - 8;
    int w7 = (((p.w >> 4) & 0xF) ^ 8) - 8;
    uint2 st;
    st.x = (uint32_t)(w0 & 0xFF) | ((uint32_t)(w1 & 0xFF) << 8) |
           ((uint32_t)(w2 & 0xFF) << 16) | ((uint32_t)(w3 & 0xFF) << 24);
    st.y = (uint32_t)(w4 & 0xFF) | ((uint32_t)(w5 & 0xFF) << 8) |
           ((uint32_t)(w6 & 0xFF) << 16) | ((uint32_t)(w7 & 0xFF) << 24);
    w8[g] = st;
  } else {
    const int g = (bx - 512) * 256 + tid;  // one float4 per thread
    const float4 v = ((const float4*)x)[g];
    int a0 = (int)rintf(fminf(fmaxf(v.x * 20.0f, -127.0f), 127.0f));
    int a1 = (int)rintf(fminf(fmaxf(v.y * 20.0f, -127.0f), 127.0f));
    int a2 = (int)rintf(fminf(fmaxf(v.z * 20.0f, -127.0f), 127.0f));
    int a3 = (int)rintf(fminf(fmaxf(v.w * 20.0f, -127.0f), 127.0f));
    q[g] = (uint32_t)(a0 & 0xFF) | ((uint32_t)(a1 & 0xFF) << 8) |
           ((uint32_t)(a2 & 0xFF) << 16) | ((uint32_t)(a3 & 0xFF) << 24);
  }
}

// ---------------- Kernel 2: int8 GEMM, producer/consumer, 2-buffer / high occupancy ----
// C[m][n] = (sum_k A[m][k]*W[n][k]) * 5e-4 + bias[n], f32 out.
// Block = 320 threads: waves 0..3 = consumers (2x2 grid of 64x64 sub-tiles,
// mfma_i32_32x32x32_i8), wave 4 = producer (global_load_lds staging only;
// consumers issue NO vm ops in the loop -> no defeating vmcnt(0) on them).
//
// r4 post-mortem drove this shape: 64KB LDS -> 1 block/CU (Occupancy 15%) and
// the per-window wall (producer L3-latency drain + barrier) had NOTHING to
// overlap with -> MfmaUtil 17.5%. Per-block MFMA content (~256-512 cyc/window)
// can never fill a ~900-cyc wall; only cross-block TLP can. So: LDS = 2 buffers
// x (8KB A + 8KB B) = 32 KB -> 4-5 blocks/CU (20-25 waves). Producer schedule:
// issue tile kk+1's 16 loads at window-kk start (buf (kk+1)&1 was released at
// barrier kk), vmcnt(0) drain + barrier at window end. Each block's drain wall
// is covered by the 3-4 other resident blocks' MFMAs.
// LDS chunk swizzle: LDS[r][c] = G[r][c ^ ((r>>1)&3)] (16B chunks) -> frag
// ds_read_b128 bank spread, staging stays lane-contiguous (gload_lds rule).
// Grid swizzle: bx&7 = XCD (round-robin dispatch) owns m-tiles [32x,32x+32) so
// each A line is L2-filled on exactly one XCD; the 8 n-blocks sharing an m-tile
// are co-resident there -> ~1x A fabric traffic.
__global__ __launch_bounds__(320, 5) void gemm_kernel(const uint8_t* __restrict__ A,
                                                      const uint8_t* __restrict__ W,
                                                      const float* __restrict__ bias,
                                                      float* __restrict__ out) {
  __shared__ uint8_t sA[2][128 * 64];
  __shared__ uint8_t sB[2][128 * 64];

  const int tid = threadIdx.x;
  const int bx = blockIdx.x;
  const int xcd = bx & 7;
  const int tt = bx >> 3;
  const int m0 = (xcd * 32 + (tt >> 3)) * 128;
  const int n0 = (tt & 7) * 128;

  if (tid >= 256) {
    // ================= producer wave =================
    const int lane = tid - 256;
    const uint8_t* gA[8];
    const uint8_t* gB[8];
    uint32_t lofs[8];
#pragma unroll
    for (int j = 0; j < 8; j++) {
      const int li = j * 64 + lane;      // chunk id within 512-chunk tile
      const int r = li >> 2, c = li & 3; // row, LDS slot
      const int cg = c ^ ((r >> 1) & 3); // swizzled global 16B chunk
      gA[j] = A + (size_t)(m0 + r) * K_DIM + cg * 16;
      gB[j] = W + (size_t)(n0 + r) * K_DIM + cg * 16;
      lofs[j] = (uint32_t)li * 16;
    }
    // Prologue: tile 0 -> buf0, drain, barrier B0.
#pragma unroll
    for (int j = 0; j < 8; j++) gload_lds16(gA[j], &sA[0][0] + lofs[j]);
#pragma unroll
    for (int j = 0; j < 8; j++) gload_lds16(gB[j], &sB[0][0] + lofs[j]);
    asm volatile("s_waitcnt vmcnt(0)\n\ts_barrier" ::: "memory");
#pragma unroll 1
    for (int kk = 0; kk < 15; kk++) {
      // Window kk: issue tile kk+1 into buf (kk+1)&1 (released at barrier kk),
      // then drain + barrier at window end. The full window covers L3 latency;
      // with 4-5 resident blocks/CU the residual drain is covered by TLP.
      const int off = (kk + 1) * 64;
      const uint32_t bo = (uint32_t)((kk + 1) & 1) * 8192;
#pragma unroll
      for (int j = 0; j < 8; j++) gload_lds16(gA[j] + off, &sA[0][0] + bo + lofs[j]);
#pragma unroll
      for (int j = 0; j < 8; j++) gload_lds16(gB[j] + off, &sB[0][0] + bo + lofs[j]);
      asm volatile("s_waitcnt vmcnt(0)\n\ts_barrier" ::: "memory");
    }
    // producer done (16 barriers total, matching consumers)
  } else {
    // ================= consumer waves =================
    const int lane = tid & 63;
    const int wid = tid >> 6;   // 0..3
    const int wm = wid >> 1;    // m-half of 128-tile
    const int wn = wid & 1;     // n-half
    const int rl = lane & 31;   // row/col within 32-tile
    const int hl = lane >> 5;   // k-half selector

    // Fragment LDS byte offsets (A: rows m, B: rows n), swizzle-corrected.
    uint32_t offA[2][2], offB[2][2];
#pragma unroll
    for (int mt = 0; mt < 2; mt++)
#pragma unroll
      for (int ks = 0; ks < 2; ks++) {
        const int rA = wm * 64 + mt * 32 + rl;
        const int ccA = (ks * 2 + hl) ^ ((rA >> 1) & 3);
        offA[mt][ks] = (uint32_t)(rA * 64 + ccA * 16);
        const int rB = wn * 64 + mt * 32 + rl;
        const int ccB = (ks * 2 + hl) ^ ((rB >> 1) & 3);
        offB[mt][ks] = (uint32_t)(rB * 64 + ccB * 16);
      }

    int32x16 acc[2][2] = {};
#pragma unroll 1
    for (int kk = 0; kk < 16; kk++) {
      asm volatile("s_barrier" ::: "memory");  // tile kk resident in buf kk&1
      const uint8_t* pA = &sA[0][0] + (uint32_t)(kk & 1) * 8192;
      const uint8_t* pB = &sB[0][0] + (uint32_t)(kk & 1) * 8192;
#pragma unroll
      for (int ks = 0; ks < 2; ks++) {
        int32x4 a0 = *(const int32x4*)(pA + offA[0][ks]);
        int32x4 a1 = *(const int32x4*)(pA + offA[1][ks]);
        int32x4 b0 = *(const int32x4*)(pB + offB[0][ks]);
        int32x4 b1 = *(const int32x4*)(pB + offB[1][ks]);
        acc[0][0] = __builtin_amdgcn_mfma_i32_32x32x32_i8(a0, b0, acc[0][0], 0, 0, 0);
        acc[0][1] = __builtin_amdgcn_mfma_i32_32x32x32_i8(a0, b1, acc[0][1], 0, 0, 0);
        acc[1][0] = __builtin_amdgcn_mfma_i32_32x32x32_i8(a1, b0, acc[1][0], 0, 0, 0);
        acc[1][1] = __builtin_amdgcn_mfma_i32_32x32x32_i8(a1, b1, acc[1][1], 0, 0, 0);
      }
    }

    // Epilogue. 32x32 C/D layout: col = lane&31, row = (reg&3) + 8*(reg>>2) + 4*(lane>>5).
    float bv[2];
#pragma unroll
    for (int nt = 0; nt < 2; nt++) bv[nt] = bias[n0 + wn * 64 + nt * 32 + rl];

#pragma unroll
    for (int mt = 0; mt < 2; mt++) {
#pragma unroll
      for (int nt = 0; nt < 2; nt++) {
        const int n_g = n0 + wn * 64 + nt * 32 + rl;
        const int mbase = m0 + wm * 64 + mt * 32 + 4 * hl;
#pragma unroll
        for (int reg = 0; reg < 16; reg++) {
          const int m_g = mbase + (reg & 3) + 8 * (reg >> 2);
          const float v = (float)acc[mt][nt][reg] * 0.0005f + bv[nt];
          // lanes 0..31 cover 32 consecutive n -> full 128B lines; write-once data.
          __builtin_nontemporal_store(v, &out[(size_t)m_g * N_DIM + n_g]);
        }
      }
    }
  }
}

extern "C" void kernel_launch(void* const* d_in, const int* in_sizes, int n_in,
                              void* d_out, int out_size, void* d_ws, size_t ws_size,
                              hipStream_t stream) {
  const float* x = (const float*)d_in[0];
  const int4* wp = (const int4*)d_in[1];   // int32 per packed byte (harness int rule)
  const float* bias = (const float*)d_in[2];
  float* out = (float*)d_out;

  uint8_t* A8 = (uint8_t*)d_ws;                       // 32768*1024 int8 = 32 MiB
  uint8_t* W8 = A8 + (size_t)M_DIM * K_DIM;           // 1024*1024 int8 = 1 MiB

  // K1: fused unpack (512 blocks) + quantize (32768 blocks)
  prep_kernel<<<512 + (M_DIM * K_DIM) / (4 * 256), 256, 0, stream>>>(
      x, wp, (uint32_t*)A8, (uint2*)W8);
  // K2: GEMM. grid = (M/128)*(N/128) = 2048, 320 threads (4 consumer + 1 producer waves)
  gemm_kernel<<<(M_DIM / 128) * (N_DIM / 128), 320, 0, stream>>>(A8, W8, bias, out);
}

// Round 8
// 266.107 us; speedup vs baseline: 1.0482x; 1.0299x over previous
//
#include <hip/hip_runtime.h>
#include <stdint.h>

// Problem constants
#define M_DIM 32768
#define N_DIM 1024
#define K_DIM 1024

using int32x4 = __attribute__((ext_vector_type(4))) int;
using int32x16 = __attribute__((ext_vector_type(16))) int;

__device__ __forceinline__ void gload_lds16(const void* g, void* l) {
  __builtin_amdgcn_global_load_lds(
      (const __attribute__((address_space(1))) void*)g,
      (__attribute__((address_space(3))) void*)l,
      16 /*bytes*/, 0 /*offset*/, 0 /*aux*/);
}

// ---------------- Kernel 1: fused weight-unpack + activation-quantize ----------------
// Blocks [0,512): unpack int4 weights -> int8 [N, K].
//   HARNESS NOTE: integer inputs arrive as int32 — weight_packed is 524288 int32
//   elements, ONE packed byte (0..255) per int32. Byte j of row r: low nibble ->
//   w[r][2j], high nibble -> w[r][2j+1]. sext4(v) = ((v&0xF)^8)-8.
// Blocks [512, 33280): quantize fp32 x -> int8: clip(rint(x*20), -127, 127).
__global__ __launch_bounds__(256) void prep_kernel(const float* __restrict__ x,
                                                   const int4* __restrict__ wp,
                                                   uint32_t* __restrict__ q,
                                                   uint2* __restrict__ w8) {
  const int bx = blockIdx.x;
  const int tid = threadIdx.x;
  if (bx < 512) {
    const int g = bx * 256 + tid;  // 4 packed bytes -> 8 int8
    const int4 p = wp[g];
    int w0 = ((p.x & 0xF) ^ 8) - 8;
    int w1 = (((p.x >> 4) & 0xF) ^ 8) - 8;
    int w2 = ((p.y & 0xF) ^ 8) - 8;
    int w3 = (((p.y >> 4) & 0xF) ^ 8) - 8;
    int w4 = ((p.z & 0xF) ^ 8) - 8;
    int w5 = (((p.z >> 4) & 0xF) ^ 8) - 8;
    int w6 = ((p.w & 0xF) ^ 8) - 8;
    int w7 = (((p.w >> 4) & 0xF) ^ 8) - 8;
    uint2 st;
    st.x = (uint32_t)(w0 & 0xFF) | ((uint32_t)(w1 & 0xFF) << 8) |
           ((uint32_t)(w2 & 0xFF) << 16) | ((uint32_t)(w3 & 0xFF) << 24);
    st.y = (uint32_t)(w4 & 0xFF) | ((uint32_t)(w5 & 0xFF) << 8) |
           ((uint32_t)(w6 & 0xFF) << 16) | ((uint32_t)(w7 & 0xFF) << 24);
    w8[g] = st;
  } else {
    const int g = (bx - 512) * 256 + tid;  // one float4 per thread
    const float4 v = ((const float4*)x)[g];
    int a0 = (int)rintf(fminf(fmaxf(v.x * 20.0f, -127.0f), 127.0f));
    int a1 = (int)rintf(fminf(fmaxf(v.y * 20.0f, -127.0f), 127.0f));
    int a2 = (int)rintf(fminf(fmaxf(v.z * 20.0f, -127.0f), 127.0f));
    int a3 = (int)rintf(fminf(fmaxf(v.w * 20.0f, -127.0f), 127.0f));
    q[g] = (uint32_t)(a0 & 0xFF) | ((uint32_t)(a1 & 0xFF) << 8) |
           ((uint32_t)(a2 & 0xFF) << 16) | ((uint32_t)(a3 & 0xFF) << 24);
  }
}

// ---------------- Kernel 2: int8 GEMM, all-wave staging + counted vmcnt ----------
// C[m][n] = (sum_k A[m][k]*W[n][k]) * 5e-4 + bias[n], f32 out.
// Block = 256 threads = 4 waves; EVERY wave both stages and computes (no
// dedicated producer). Per 128x64 K-tile there are 16 wave-loads (A 8 + B 8);
// wave w stages 4 of them (rows [32w, 32w+32) of A and of B). vmcnt is
// per-wave, so each wave applies r0's proven never-drain discipline to its own
// loads: wait vmcnt(4) (my tile-kk loads done, my tile-kk+1 loads may fly),
// raw s_barrier, issue tile kk+2 (distance 2), then ds_read+MFMA tile kk.
// Ledger: r0 (producer wave, vmcnt(16), 3buf) = 262 | 2-buf drain-per-window =
// 274 (r7: full L2 latency on every window) | BK=128/64KB = 279 (1 block/CU,
// no TLP cover). This keeps r0's {3 buffers, 48KB -> 3 blocks/CU, distance-2,
// counted vmcnt} and removes the producer-wave asymmetry: staging issue is
// parallelized 4x and overlaps each wave's own MFMAs; 256 threads = 1 wave/SIMD
// x 3 blocks = clean 3 waves/SIMD.
// Race audit: identical code path for all waves (barrier counts match); buffer
// (kk+2)%3 held tile kk-1, fully consumed (lgkmcnt-drained into window kk-1's
// MFMAs) before barrier kk; vmcnt(4) pre-barrier on every wave => all 16 loads
// of tile kk are in LDS when barrier kk opens.
// LDS chunk swizzle: LDS[r][c] = G[r][c ^ ((r>>1)&3)] (16B chunks) -> frag
// ds_read_b128 lands 2-way bank aliasing (free), staging stays lane-contiguous.
// Grid swizzle: bx&7 = XCD (round-robin dispatch) owns m-tiles [32x,32x+32) so
// each A line is L2-filled on exactly one XCD; the 8 n-blocks sharing an m-tile
// are co-resident there -> ~1x A fabric traffic.
__global__ __launch_bounds__(256, 3) void gemm_kernel(const uint8_t* __restrict__ A,
                                                      const uint8_t* __restrict__ W,
                                                      const float* __restrict__ bias,
                                                      float* __restrict__ out) {
  __shared__ uint8_t sA[3][128 * 64];
  __shared__ uint8_t sB[3][128 * 64];

  const int tid = threadIdx.x;
  const int bx = blockIdx.x;
  const int xcd = bx & 7;
  const int tt = bx >> 3;
  const int m0 = (xcd * 32 + (tt >> 3)) * 128;
  const int n0 = (tt & 7) * 128;

  const int lane = tid & 63;
  const int wid = tid >> 6;   // 0..3
  const int wm = wid >> 1;    // m-half of 128-tile (compute role)
  const int wn = wid & 1;     // n-half
  const int rl = lane & 31;   // row/col within 32-tile
  const int hl = lane >> 5;   // k-half selector

  // ---- staging role: wave wid owns A rows [32*wid, 32*wid+32) and B same ----
  const uint8_t* gA[2];
  const uint8_t* gB[2];
  uint32_t lofs[2];
#pragma unroll
  for (int j = 0; j < 2; j++) {
    const int li = wid * 128 + j * 64 + lane;  // chunk id within 512-chunk tile
    const int r = li >> 2, c = li & 3;         // row, LDS slot
    const int cg = c ^ ((r >> 1) & 3);         // swizzled global 16B chunk
    gA[j] = A + (size_t)(m0 + r) * K_DIM + cg * 16;
    gB[j] = W + (size_t)(n0 + r) * K_DIM + cg * 16;
    lofs[j] = (uint32_t)li * 16;
  }

  // ---- compute role: fragment LDS byte offsets, swizzle-corrected ----
  uint32_t offA[2][2], offB[2][2];
#pragma unroll
  for (int mt = 0; mt < 2; mt++)
#pragma unroll
    for (int ks = 0; ks < 2; ks++) {
      const int rA = wm * 64 + mt * 32 + rl;
      const int ccA = (ks * 2 + hl) ^ ((rA >> 1) & 3);
      offA[mt][ks] = (uint32_t)(rA * 64 + ccA * 16);
      const int rB = wn * 64 + mt * 32 + rl;
      const int ccB = (ks * 2 + hl) ^ ((rB >> 1) & 3);
      offB[mt][ks] = (uint32_t)(rB * 64 + ccB * 16);
    }

  // Prologue: issue tile 0 -> buf0 and tile 1 -> buf1 (8 loads in flight/wave).
#pragma unroll
  for (int j = 0; j < 2; j++) {
    gload_lds16(gA[j], &sA[0][0] + lofs[j]);
    gload_lds16(gB[j], &sB[0][0] + lofs[j]);
  }
#pragma unroll
  for (int j = 0; j < 2; j++) {
    gload_lds16(gA[j] + 64, &sA[1][0] + lofs[j]);
    gload_lds16(gB[j] + 64, &sB[1][0] + lofs[j]);
  }

  int32x16 acc[2][2] = {};
#pragma unroll 1
  for (int kk = 0; kk < 16; kk++) {
    // My tile-kk loads complete (tile kk+1's 4 may stay in flight), then barrier.
    if (kk < 15) {
      asm volatile("s_waitcnt vmcnt(4)\n\ts_barrier" ::: "memory");
    } else {
      asm volatile("s_waitcnt vmcnt(0)\n\ts_barrier" ::: "memory");
    }
    if (kk < 14) {  // issue tile kk+2 into buf (kk+2)%3 (freed: tile kk-1 consumed)
      const int off = (kk + 2) * 64;
      const uint32_t bo = (uint32_t)((kk + 2) % 3) * 8192;
#pragma unroll
      for (int j = 0; j < 2; j++) {
        gload_lds16(gA[j] + off, &sA[0][0] + bo + lofs[j]);
        gload_lds16(gB[j] + off, &sB[0][0] + bo + lofs[j]);
      }
    }
    const uint32_t cb = (uint32_t)(kk % 3) * 8192;
    const uint8_t* pA = &sA[0][0] + cb;
    const uint8_t* pB = &sB[0][0] + cb;
#pragma unroll
    for (int ks = 0; ks < 2; ks++) {
      int32x4 a0 = *(const int32x4*)(pA + offA[0][ks]);
      int32x4 a1 = *(const int32x4*)(pA + offA[1][ks]);
      int32x4 b0 = *(const int32x4*)(pB + offB[0][ks]);
      int32x4 b1 = *(const int32x4*)(pB + offB[1][ks]);
      acc[0][0] = __builtin_amdgcn_mfma_i32_32x32x32_i8(a0, b0, acc[0][0], 0, 0, 0);
      acc[0][1] = __builtin_amdgcn_mfma_i32_32x32x32_i8(a0, b1, acc[0][1], 0, 0, 0);
      acc[1][0] = __builtin_amdgcn_mfma_i32_32x32x32_i8(a1, b0, acc[1][0], 0, 0, 0);
      acc[1][1] = __builtin_amdgcn_mfma_i32_32x32x32_i8(a1, b1, acc[1][1], 0, 0, 0);
    }
  }

  // Epilogue. 32x32 C/D layout: col = lane&31, row = (reg&3) + 8*(reg>>2) + 4*(lane>>5).
  float bv[2];
#pragma unroll
  for (int nt = 0; nt < 2; nt++) bv[nt] = bias[n0 + wn * 64 + nt * 32 + rl];

#pragma unroll
  for (int mt = 0; mt < 2; mt++) {
#pragma unroll
    for (int nt = 0; nt < 2; nt++) {
      const int n_g = n0 + wn * 64 + nt * 32 + rl;
      const int mbase = m0 + wm * 64 + mt * 32 + 4 * hl;
#pragma unroll
      for (int reg = 0; reg < 16; reg++) {
        const int m_g = mbase + (reg & 3) + 8 * (reg >> 2);
        const float v = (float)acc[mt][nt][reg] * 0.0005f + bv[nt];
        // lanes 0..31 cover 32 consecutive n -> full 128B lines; write-once data.
        __builtin_nontemporal_store(v, &out[(size_t)m_g * N_DIM + n_g]);
      }
    }
  }
}

extern "C" void kernel_launch(void* const* d_in, const int* in_sizes, int n_in,
                              void* d_out, int out_size, void* d_ws, size_t ws_size,
                              hipStream_t stream) {
  const float* x = (const float*)d_in[0];
  const int4* wp = (const int4*)d_in[1];   // int32 per packed byte (harness int rule)
  const float* bias = (const float*)d_in[2];
  float* out = (float*)d_out;

  uint8_t* A8 = (uint8_t*)d_ws;                       // 32768*1024 int8 = 32 MiB
  uint8_t* W8 = A8 + (size_t)M_DIM * K_DIM;           // 1024*1024 int8 = 1 MiB

  // K1: fused unpack (512 blocks) + quantize (32768 blocks)
  prep_kernel<<<512 + (M_DIM * K_DIM) / (4 * 256), 256, 0, stream>>>(
      x, wp, (uint32_t*)A8, (uint2*)W8);
  // K2: GEMM. grid = (M/128)*(N/128) = 2048, 256 threads (4 waves, all stage+compute)
  gemm_kernel<<<(M_DIM / 128) * (N_DIM / 128), 256, 0, stream>>>(A8, W8, bias, out);
}